// Round 1
// baseline (1017.347 us; speedup 1.0000x reference)
//
#include <hip/hip_runtime.h>

constexpr int NPIX  = 1 << 20;   // 1024*1024 pixels
constexpr int NCLS  = 21;
constexpr int NBINS = 32768;     // linear bins over [0,16): width = 4.88e-4
constexpr float BIN_SCALE = NBINS / 16.0f;

// ---------------------------------------------------------------------------
// 1) per-pixel argmax over classes (first occurrence of max, like jnp.argmax)
// ---------------------------------------------------------------------------
__global__ void k_argmax(const int* __restrict__ label, int* __restrict__ lbl) {
    int i = blockIdx.x * blockDim.x + threadIdx.x;
    if (i >= NPIX) return;
    int best = label[i];
    int bc = 0;
    #pragma unroll
    for (int c = 1; c < NCLS; ++c) {
        int v = label[c * NPIX + i];
        if (v > best) { best = v; bc = c; }   // strict > keeps FIRST max
    }
    lbl[i] = bc;
}

// ---------------------------------------------------------------------------
// 2) per-class histogram of quantized errors; u64 packs (n_total | n_fg<<32)
// ---------------------------------------------------------------------------
__global__ void k_hist(const float* __restrict__ pred, const int* __restrict__ lbl,
                       unsigned long long* __restrict__ hist) {
    const long long total  = (long long)NCLS * NPIX;
    const long long stride = (long long)gridDim.x * blockDim.x;
    for (long long idx = blockIdx.x * (long long)blockDim.x + threadIdx.x;
         idx < total; idx += stride) {
        int c = (int)(idx >> 20);            // NPIX = 2^20
        int i = (int)idx & (NPIX - 1);
        float p = pred[idx];                 // flat layout == prediction[c][i]
        int fg = (lbl[i] == c) ? 1 : 0;
        float e = fabsf((float)fg - p);
        int bin = (int)(e * BIN_SCALE);
        bin = bin < NBINS - 1 ? bin : NBINS - 1;
        atomicAdd(&hist[((size_t)c << 15) + bin],
                  1ULL | ((unsigned long long)fg << 32));
    }
}

// ---------------------------------------------------------------------------
// 3) per-class descending scan over bins; Lovasz loss via j = i/(G+i-F)
//    one block (1024 threads) per class; 32 bins per thread
// ---------------------------------------------------------------------------
__global__ void __launch_bounds__(1024)
k_scan(const unsigned long long* __restrict__ hist, double* __restrict__ losses) {
    const int c = blockIdx.x;
    const int t = threadIdx.x;
    const unsigned long long* h = hist + ((size_t)c << 15);
    constexpr int BPT = NBINS / 1024;        // 32 bins per thread

    __shared__ unsigned int sn[1024], sf[1024];

    // per-thread sums over its rank range (rank r: 0 = largest error bin)
    unsigned int tn = 0, tf = 0;
    for (int k = 0; k < BPT; ++k) {
        int r = t * BPT + k;
        unsigned long long v = h[NBINS - 1 - r];
        tn += (unsigned int)v;
        tf += (unsigned int)(v >> 32);
    }
    sn[t] = tn; sf[t] = tf;
    __syncthreads();

    // block inclusive scan (Hillis-Steele) over 1024 thread sums
    for (int off = 1; off < 1024; off <<= 1) {
        unsigned int an = 0, af = 0;
        if (t >= off) { an = sn[t - off]; af = sf[t - off]; }
        __syncthreads();
        if (t >= off) { sn[t] += an; sf[t] += af; }
        __syncthreads();
    }

    const unsigned int G = sf[1023];         // total foreground count
    unsigned int i = sn[t] - tn;             // exclusive prefix (descending order)
    unsigned int F = sf[t] - tf;

    double jprev = (i > 0) ? (double)i / (double)(G + i - F) : 0.0;
    double acc = 0.0;
    for (int k = 0; k < BPT; ++k) {
        int r = t * BPT + k;
        int bin = NBINS - 1 - r;
        unsigned long long v = h[bin];
        unsigned int n = (unsigned int)v;
        if (n) {
            unsigned int nf = (unsigned int)(v >> 32);
            i += n; F += nf;
            double jhi = (double)i / (double)(G + i - F);
            double eb  = (bin + 0.5) * (16.0 / NBINS);   // bin-center error
            acc += eb * (jhi - jprev);
            jprev = jhi;
        }
    }

    // block reduce the per-thread contributions (double)
    __shared__ double sd[1024];
    sd[t] = acc;
    __syncthreads();
    for (int off = 512; off > 0; off >>= 1) {
        if (t < off) sd[t] += sd[t + off];
        __syncthreads();
    }
    if (t == 0) losses[c] = sd[0];
}

// ---------------------------------------------------------------------------
// 4) mean over classes
// ---------------------------------------------------------------------------
__global__ void k_final(const double* __restrict__ losses, float* __restrict__ out) {
    if (threadIdx.x == 0 && blockIdx.x == 0) {
        double s = 0.0;
        for (int c = 0; c < NCLS; ++c) s += losses[c];
        out[0] = (float)(s / NCLS);
    }
}

extern "C" void kernel_launch(void* const* d_in, const int* in_sizes, int n_in,
                              void* d_out, int out_size, void* d_ws, size_t ws_size,
                              hipStream_t stream) {
    const float* pred  = (const float*)d_in[0];
    const int*   label = (const int*)d_in[1];
    float* out = (float*)d_out;

    char* ws = (char*)d_ws;
    int* lbl = (int*)ws;                                             // 4 MiB
    size_t off_hist = (size_t)NPIX * sizeof(int);
    unsigned long long* hist = (unsigned long long*)(ws + off_hist); // 5.25 MiB
    size_t off_loss = off_hist + (size_t)NCLS * NBINS * sizeof(unsigned long long);
    double* losses = (double*)(ws + off_loss);                       // 168 B

    hipMemsetAsync(hist, 0, (size_t)NCLS * NBINS * sizeof(unsigned long long), stream);
    k_argmax<<<NPIX / 256, 256, 0, stream>>>(label, lbl);
    k_hist<<<4096, 256, 0, stream>>>(pred, lbl, hist);
    k_scan<<<NCLS, 1024, 0, stream>>>(hist, losses);
    k_final<<<1, 64, 0, stream>>>(losses, out);
}

// Round 2
// 76.746 us; speedup vs baseline: 13.2560x; 13.2560x over previous
//
#include <hip/hip_runtime.h>

constexpr int NPIX  = 1 << 20;   // 1024*1024 pixels
constexpr int NCLS  = 21;
constexpr int NBINS = 16384;     // linear bins over [0,16): width = 9.77e-4
constexpr float RANGE = 16.0f;
constexpr float BIN_SCALE = NBINS / RANGE;

// ---------------------------------------------------------------------------
// 1) per-pixel argmax over classes (first occurrence of max, like jnp.argmax)
//    int4-vectorized: each thread owns 4 pixels.
// ---------------------------------------------------------------------------
__global__ void k_argmax(const int4* __restrict__ label, int4* __restrict__ lbl) {
    int i = blockIdx.x * blockDim.x + threadIdx.x;     // over NPIX/4
    if (i >= NPIX / 4) return;
    int4 best = label[i];
    int4 bc = make_int4(0, 0, 0, 0);
    #pragma unroll
    for (int c = 1; c < NCLS; ++c) {
        int4 v = label[(size_t)c * (NPIX / 4) + i];
        if (v.x > best.x) { best.x = v.x; bc.x = c; }  // strict > keeps FIRST max
        if (v.y > best.y) { best.y = v.y; bc.y = c; }
        if (v.z > best.z) { best.z = v.z; bc.z = c; }
        if (v.w > best.w) { best.w = v.w; bc.w = c; }
    }
    lbl[i] = bc;
}

// ---------------------------------------------------------------------------
// 2) per-(class,chunk) LDS-private histogram; u32 packs (n | n_fg<<16).
//    Flush = plain coalesced stores (NO global atomics).
// ---------------------------------------------------------------------------
__global__ void __launch_bounds__(512)
k_hist(const float4* __restrict__ pred4, const int4* __restrict__ lbl4,
       unsigned int* __restrict__ part, int nchunk) {
    extern __shared__ unsigned int sh[];               // NBINS u32
    const int chunk = blockIdx.x;
    const int c     = blockIdx.y;
    const int t     = threadIdx.x;
    const int chunkPix = NPIX / nchunk;

    for (int b = t; b < NBINS; b += blockDim.x) sh[b] = 0u;
    __syncthreads();

    const size_t pbase4 = ((size_t)c * NPIX + (size_t)chunk * chunkPix) / 4;
    const size_t lbase4 = ((size_t)chunk * chunkPix) / 4;
    const int n4 = chunkPix / 4;

    for (int k = t; k < n4; k += blockDim.x) {
        float4 p = pred4[pbase4 + k];
        int4   l = lbl4[lbase4 + k];
        {
            unsigned int fg = (l.x == c) ? 1u : 0u;
            float e = fabsf((float)fg - p.x);
            int bin = (int)(e * BIN_SCALE); bin = bin < NBINS - 1 ? bin : NBINS - 1;
            atomicAdd(&sh[bin], 1u | (fg << 16));
        }
        {
            unsigned int fg = (l.y == c) ? 1u : 0u;
            float e = fabsf((float)fg - p.y);
            int bin = (int)(e * BIN_SCALE); bin = bin < NBINS - 1 ? bin : NBINS - 1;
            atomicAdd(&sh[bin], 1u | (fg << 16));
        }
        {
            unsigned int fg = (l.z == c) ? 1u : 0u;
            float e = fabsf((float)fg - p.z);
            int bin = (int)(e * BIN_SCALE); bin = bin < NBINS - 1 ? bin : NBINS - 1;
            atomicAdd(&sh[bin], 1u | (fg << 16));
        }
        {
            unsigned int fg = (l.w == c) ? 1u : 0u;
            float e = fabsf((float)fg - p.w);
            int bin = (int)(e * BIN_SCALE); bin = bin < NBINS - 1 ? bin : NBINS - 1;
            atomicAdd(&sh[bin], 1u | (fg << 16));
        }
    }
    __syncthreads();

    unsigned int* dst = part + ((size_t)c * nchunk + chunk) * NBINS;
    for (int b = t; b < NBINS; b += blockDim.x) dst[b] = sh[b];   // coalesced
}

// ---------------------------------------------------------------------------
// 3) merge chunk partials -> per-class u64 hist (n | n_fg<<32), coalesced
// ---------------------------------------------------------------------------
__global__ void k_merge(const unsigned int* __restrict__ part,
                        unsigned long long* __restrict__ hist, int nchunk) {
    int b = blockIdx.x * blockDim.x + threadIdx.x;     // over NCLS*NBINS
    if (b >= NCLS * NBINS) return;
    int c = b / NBINS, bin = b % NBINS;
    unsigned int n = 0, f = 0;
    for (int k = 0; k < nchunk; ++k) {
        unsigned int v = part[((size_t)c * nchunk + k) * NBINS + bin];
        n += v & 0xFFFFu;
        f += v >> 16;
    }
    hist[b] = (unsigned long long)n | ((unsigned long long)f << 32);
}

// ---------------------------------------------------------------------------
// 4) per-class descending scan over bins; Lovasz loss via j = i/(G+i-F)
// ---------------------------------------------------------------------------
__global__ void __launch_bounds__(1024)
k_scan(const unsigned long long* __restrict__ hist, double* __restrict__ losses) {
    const int c = blockIdx.x;
    const int t = threadIdx.x;
    const unsigned long long* h = hist + (size_t)c * NBINS;
    constexpr int BPT = NBINS / 1024;                  // 16 bins per thread

    __shared__ unsigned int sn[1024], sf[1024];

    unsigned int tn = 0, tf = 0;
    for (int k = 0; k < BPT; ++k) {
        unsigned long long v = h[NBINS - 1 - (t * BPT + k)];
        tn += (unsigned int)v;
        tf += (unsigned int)(v >> 32);
    }
    sn[t] = tn; sf[t] = tf;
    __syncthreads();

    for (int off = 1; off < 1024; off <<= 1) {         // Hillis-Steele scan
        unsigned int an = 0, af = 0;
        if (t >= off) { an = sn[t - off]; af = sf[t - off]; }
        __syncthreads();
        if (t >= off) { sn[t] += an; sf[t] += af; }
        __syncthreads();
    }

    const unsigned int G = sf[1023];
    unsigned int i = sn[t] - tn;                       // exclusive prefix
    unsigned int F = sf[t] - tf;

    double jprev = (i > 0) ? (double)i / (double)(G + i - F) : 0.0;
    double acc = 0.0;
    for (int k = 0; k < BPT; ++k) {
        int bin = NBINS - 1 - (t * BPT + k);
        unsigned long long v = h[bin];
        unsigned int n = (unsigned int)v;
        if (n) {
            unsigned int nf = (unsigned int)(v >> 32);
            i += n; F += nf;
            double jhi = (double)i / (double)(G + i - F);
            double eb  = (bin + 0.5) * (double)(RANGE / NBINS);
            acc += eb * (jhi - jprev);
            jprev = jhi;
        }
    }

    __shared__ double sd[1024];
    sd[t] = acc;
    __syncthreads();
    for (int off = 512; off > 0; off >>= 1) {
        if (t < off) sd[t] += sd[t + off];
        __syncthreads();
    }
    if (t == 0) losses[c] = sd[0];
}

// ---------------------------------------------------------------------------
// 5) mean over classes
// ---------------------------------------------------------------------------
__global__ void k_final(const double* __restrict__ losses, float* __restrict__ out) {
    if (threadIdx.x == 0 && blockIdx.x == 0) {
        double s = 0.0;
        for (int c = 0; c < NCLS; ++c) s += losses[c];
        out[0] = (float)(s / NCLS);
    }
}

extern "C" void kernel_launch(void* const* d_in, const int* in_sizes, int n_in,
                              void* d_out, int out_size, void* d_ws, size_t ws_size,
                              hipStream_t stream) {
    const float* pred  = (const float*)d_in[0];
    const int*   label = (const int*)d_in[1];
    float* out = (float*)d_out;

    // pick nchunk to fit workspace: lbl + part + hist + losses
    int nchunk = 32;
    auto need = [](int nc) {
        return (size_t)NPIX * 4
             + (size_t)NCLS * nc * NBINS * 4
             + (size_t)NCLS * NBINS * 8
             + (size_t)NCLS * 8;
    };
    while (nchunk > 1 && need(nchunk) > ws_size) nchunk >>= 1;

    char* ws = (char*)d_ws;
    int* lbl = (int*)ws;
    size_t off = (size_t)NPIX * 4;
    unsigned int* part = (unsigned int*)(ws + off);
    off += (size_t)NCLS * nchunk * NBINS * 4;
    unsigned long long* hist = (unsigned long long*)(ws + off);
    off += (size_t)NCLS * NBINS * 8;
    double* losses = (double*)(ws + off);

    k_argmax<<<NPIX / 4 / 256, 256, 0, stream>>>((const int4*)label, (int4*)lbl);
    dim3 hgrid(nchunk, NCLS);
    k_hist<<<hgrid, 512, NBINS * sizeof(unsigned int), stream>>>(
        (const float4*)pred, (const int4*)lbl, part, nchunk);
    k_merge<<<(NCLS * NBINS + 255) / 256, 256, 0, stream>>>(part, hist, nchunk);
    k_scan<<<NCLS, 1024, 0, stream>>>(hist, losses);
    k_final<<<1, 64, 0, stream>>>(losses, out);
}

// Round 3
// 52.014 us; speedup vs baseline: 19.5591x; 1.4755x over previous
//
#include <hip/hip_runtime.h>

constexpr int NPIX  = 1 << 20;   // 1024*1024 pixels
constexpr int NCLS  = 21;
constexpr int NBINS = 8192;      // linear bins over [0,16): width = 1.95e-3
constexpr float RANGE = 16.0f;
constexpr float BIN_SCALE = NBINS / RANGE;

// ---------------------------------------------------------------------------
// 1) per-pixel argmax over classes (first occurrence of max, like jnp.argmax)
//    int4-vectorized; result packed to uchar (1 MB -> L2-resident re-reads)
// ---------------------------------------------------------------------------
__global__ void k_argmax(const int4* __restrict__ label, uchar4* __restrict__ lbl) {
    int i = blockIdx.x * blockDim.x + threadIdx.x;     // over NPIX/4
    if (i >= NPIX / 4) return;
    int4 best = label[i];
    int bx = 0, by = 0, bz = 0, bw = 0;
    #pragma unroll
    for (int c = 1; c < NCLS; ++c) {
        int4 v = label[(size_t)c * (NPIX / 4) + i];
        if (v.x > best.x) { best.x = v.x; bx = c; }    // strict > keeps FIRST max
        if (v.y > best.y) { best.y = v.y; by = c; }
        if (v.z > best.z) { best.z = v.z; bz = c; }
        if (v.w > best.w) { best.w = v.w; bw = c; }
    }
    lbl[i] = make_uchar4((unsigned char)bx, (unsigned char)by,
                         (unsigned char)bz, (unsigned char)bw);
}

// ---------------------------------------------------------------------------
// 2) per-(class,chunk) LDS-private histogram; u32 packs (n | n_fg<<16).
//    chunkPix = 32768 so both fields fit u16. Flush = coalesced uint4 stores.
// ---------------------------------------------------------------------------
__global__ void __launch_bounds__(512)
k_hist(const float4* __restrict__ pred4, const uchar4* __restrict__ lbl4,
       unsigned int* __restrict__ part, int nchunk) {
    __shared__ unsigned int sh[NBINS];                 // 32 KB
    const int chunk = blockIdx.x;
    const int c     = blockIdx.y;
    const int t     = threadIdx.x;
    const int chunkPix = NPIX / nchunk;

    for (int b = t; b < NBINS; b += 512) sh[b] = 0u;
    __syncthreads();

    const size_t pbase4 = ((size_t)c * NPIX + (size_t)chunk * chunkPix) / 4;
    const size_t lbase4 = ((size_t)chunk * chunkPix) / 4;
    const int n4 = chunkPix / 4;

    for (int k = t; k < n4; k += 512) {
        float4 p = pred4[pbase4 + k];
        uchar4 l = lbl4[lbase4 + k];
        {
            unsigned int fg = (l.x == c) ? 1u : 0u;
            float e = fabsf((float)fg - p.x);
            int bin = (int)(e * BIN_SCALE); bin = bin < NBINS - 1 ? bin : NBINS - 1;
            atomicAdd(&sh[bin], 1u | (fg << 16));
        }
        {
            unsigned int fg = (l.y == c) ? 1u : 0u;
            float e = fabsf((float)fg - p.y);
            int bin = (int)(e * BIN_SCALE); bin = bin < NBINS - 1 ? bin : NBINS - 1;
            atomicAdd(&sh[bin], 1u | (fg << 16));
        }
        {
            unsigned int fg = (l.z == c) ? 1u : 0u;
            float e = fabsf((float)fg - p.z);
            int bin = (int)(e * BIN_SCALE); bin = bin < NBINS - 1 ? bin : NBINS - 1;
            atomicAdd(&sh[bin], 1u | (fg << 16));
        }
        {
            unsigned int fg = (l.w == c) ? 1u : 0u;
            float e = fabsf((float)fg - p.w);
            int bin = (int)(e * BIN_SCALE); bin = bin < NBINS - 1 ? bin : NBINS - 1;
            atomicAdd(&sh[bin], 1u | (fg << 16));
        }
    }
    __syncthreads();

    uint4* dst = (uint4*)(part + ((size_t)c * nchunk + chunk) * NBINS);
    const uint4* src = (const uint4*)sh;
    for (int b = t; b < NBINS / 4; b += 512) dst[b] = src[b];   // coalesced 16B
}

// ---------------------------------------------------------------------------
// 3) merge chunk partials -> per-class u64 hist (n | n_fg<<32), coalesced
// ---------------------------------------------------------------------------
__global__ void k_merge(const unsigned int* __restrict__ part,
                        unsigned long long* __restrict__ hist, int nchunk) {
    int b = blockIdx.x * blockDim.x + threadIdx.x;     // over NCLS*NBINS
    if (b >= NCLS * NBINS) return;
    int c = b / NBINS, bin = b % NBINS;
    unsigned int n = 0, f = 0;
    for (int k = 0; k < nchunk; ++k) {
        unsigned int v = part[((size_t)c * nchunk + k) * NBINS + bin];
        n += v & 0xFFFFu;
        f += v >> 16;
    }
    hist[b] = (unsigned long long)n | ((unsigned long long)f << 32);
}

// ---------------------------------------------------------------------------
// 4) per-class descending scan over bins; Lovasz loss via j = i/(G+i-F)
// ---------------------------------------------------------------------------
__global__ void __launch_bounds__(1024)
k_scan(const unsigned long long* __restrict__ hist, double* __restrict__ losses) {
    const int c = blockIdx.x;
    const int t = threadIdx.x;
    const unsigned long long* h = hist + (size_t)c * NBINS;
    constexpr int BPT = NBINS / 1024;                  // 8 bins per thread

    __shared__ unsigned int sn[1024], sf[1024];

    unsigned int tn = 0, tf = 0;
    for (int k = 0; k < BPT; ++k) {
        unsigned long long v = h[NBINS - 1 - (t * BPT + k)];
        tn += (unsigned int)v;
        tf += (unsigned int)(v >> 32);
    }
    sn[t] = tn; sf[t] = tf;
    __syncthreads();

    for (int off = 1; off < 1024; off <<= 1) {         // Hillis-Steele scan
        unsigned int an = 0, af = 0;
        if (t >= off) { an = sn[t - off]; af = sf[t - off]; }
        __syncthreads();
        if (t >= off) { sn[t] += an; sf[t] += af; }
        __syncthreads();
    }

    const unsigned int G = sf[1023];
    unsigned int i = sn[t] - tn;                       // exclusive prefix
    unsigned int F = sf[t] - tf;

    double jprev = (i > 0) ? (double)i / (double)(G + i - F) : 0.0;
    double acc = 0.0;
    for (int k = 0; k < BPT; ++k) {
        int bin = NBINS - 1 - (t * BPT + k);
        unsigned long long v = h[bin];
        unsigned int n = (unsigned int)v;
        if (n) {
            unsigned int nf = (unsigned int)(v >> 32);
            i += n; F += nf;
            double jhi = (double)i / (double)(G + i - F);
            double eb  = (bin + 0.5) * (double)(RANGE / NBINS);
            acc += eb * (jhi - jprev);
            jprev = jhi;
        }
    }

    __shared__ double sd[1024];
    sd[t] = acc;
    __syncthreads();
    for (int off = 512; off > 0; off >>= 1) {
        if (t < off) sd[t] += sd[t + off];
        __syncthreads();
    }
    if (t == 0) losses[c] = sd[0];
}

// ---------------------------------------------------------------------------
// 5) mean over classes
// ---------------------------------------------------------------------------
__global__ void k_final(const double* __restrict__ losses, float* __restrict__ out) {
    if (threadIdx.x == 0 && blockIdx.x == 0) {
        double s = 0.0;
        for (int c = 0; c < NCLS; ++c) s += losses[c];
        out[0] = (float)(s / NCLS);
    }
}

extern "C" void kernel_launch(void* const* d_in, const int* in_sizes, int n_in,
                              void* d_out, int out_size, void* d_ws, size_t ws_size,
                              hipStream_t stream) {
    const float* pred  = (const float*)d_in[0];
    const int*   label = (const int*)d_in[1];
    float* out = (float*)d_out;

    // pick nchunk to fit workspace: lbl(uchar) + part + hist + losses
    int nchunk = 32;
    auto need = [](int nc) {
        return (size_t)NPIX
             + (size_t)NCLS * nc * NBINS * 4
             + (size_t)NCLS * NBINS * 8
             + (size_t)NCLS * 8;
    };
    while (nchunk > 1 && need(nchunk) > ws_size) nchunk >>= 1;

    char* ws = (char*)d_ws;
    unsigned char* lbl = (unsigned char*)ws;
    size_t off = (size_t)NPIX;
    unsigned int* part = (unsigned int*)(ws + off);
    off += (size_t)NCLS * nchunk * NBINS * 4;
    unsigned long long* hist = (unsigned long long*)(ws + off);
    off += (size_t)NCLS * NBINS * 8;
    double* losses = (double*)(ws + off);

    k_argmax<<<NPIX / 4 / 256, 256, 0, stream>>>((const int4*)label, (uchar4*)lbl);
    dim3 hgrid(nchunk, NCLS);
    k_hist<<<hgrid, 512, 0, stream>>>((const float4*)pred, (const uchar4*)lbl,
                                      part, nchunk);
    k_merge<<<(NCLS * NBINS + 255) / 256, 256, 0, stream>>>(part, hist, nchunk);
    k_scan<<<NCLS, 1024, 0, stream>>>(hist, losses);
    k_final<<<1, 64, 0, stream>>>(losses, out);
}